// Round 5
// baseline (1559.740 us; speedup 1.0000x reference)
//
#include <hip/hip_runtime.h>
#include <hip/hip_cooperative_groups.h>

namespace cg = cooperative_groups;

#define NN 96
#define N3 (96*96*96)
#define NT 2304            // tiles: 96 x-slabs * 24 y-groups(of 4)
#define EPS 0.0025f
#define DT  0.1f

__device__ __forceinline__ int wm(int i){ return i==0    ? NN-1 : i-1; }
__device__ __forceinline__ int wp(int i){ return i==NN-1 ? 0    : i+1; }
__device__ __forceinline__ int IDX(int x,int y,int z){ return (x*NN+y)*NN+z; }

__device__ __forceinline__ float Lop(const float* __restrict__ s,
    int xm,int x,int xp, int ym,int y,int yp, int zm,int z,int zp){
  float c = s[IDX(x,y,z)];
  float sum = s[IDX(xm,y,z)] + s[IDX(xp,y,z)]
            + s[IDX(x,ym,z)] + s[IDX(x,yp,z)]
            + s[IDX(x,y,zm)] + s[IDX(x,y,zp)];
  return fmaf(EPS, 6.0f*c - sum, c);
}

__global__ __launch_bounds__(384) void mega(const float* __restrict__ v0,
    float* __restrict__ v, float* __restrict__ disA, float* __restrict__ disB,
    float* __restrict__ tb, float* __restrict__ out)
{
  cg::grid_group grid = cg::this_grid();
  const int G   = gridDim.x;
  const int z   = threadIdx.x;
  const int tid = threadIdx.y*NN + threadIdx.x;

  // phase 0: AoS f32 -> SoA f32
  for (int i = blockIdx.x*384 + tid; i < N3; i += G*384){
    v[i]      = v0[3*i];
    v[N3+i]   = v0[3*i+1];
    v[2*N3+i] = v0[3*i+2];
  }

  float* dcur  = disA;
  float* dfree = disB;

  for (int s = 0; s < 10; s++){
    __threadfence();
    grid.sync();

    const float* din = dcur;
    float* dout = (s==0) ? dcur : dfree;

    // ---- phase A: dis update + t = t1+t2 (m = Lv on the fly) ----
    for (int t = blockIdx.x; t < NT; t += G){
      const int x = t/24;
      const int y = (t%24)*4 + threadIdx.y;
      const int xm=wm(x), xp=wp(x), xm2=wm(xm), xp2=wp(xp);
      const int ym=wm(y), yp=wp(y), ym2=wm(ym), yp2=wp(yp);
      const int zm=wm(z), zp=wp(z), zm2=wm(zm), zp2=wp(zp);
      const int p = IDX(x,y,z);

      float vv[3] = { v[p], v[N3+p], v[2*N3+p] };

      #pragma unroll
      for (int c=0;c<3;c++){
        float r;
        if (s == 0){
          r = -DT*vv[c];
        } else {
          const float* d = din + c*N3;
          float gx = 0.5f*(d[IDX(xp,y,z)] - d[IDX(xm,y,z)]);
          float gy = 0.5f*(d[IDX(x,yp,z)] - d[IDX(x,ym,z)]);
          float gz = 0.5f*(d[IDX(x,y,zp)] - d[IDX(x,y,zm)]);
          float w  = gx*vv[0] + gy*vv[1] + gz*vv[2];
          r = d[p] - DT*(w + vv[c]);
        }
        if (s == 9) out[(size_t)p*3+c] = r;
        else        dout[c*N3+p]       = r;
      }
      if (s == 9) continue;

      float mc[3], mxm[3], mxp[3], mym[3], myp[3], mzm[3], mzp[3];
      float vxm[3], vxp[3], vym[3], vyp[3], vzm[3], vzp[3];
      #pragma unroll
      for (int c=0;c<3;c++){
        const float* sv = v + c*N3;
        mc [c] = Lop(sv, xm,x,xp,   ym,y,yp,   zm,z,zp);
        mxm[c] = Lop(sv, xm2,xm,x,  ym,y,yp,   zm,z,zp);
        mxp[c] = Lop(sv, x,xp,xp2,  ym,y,yp,   zm,z,zp);
        mym[c] = Lop(sv, xm,x,xp,   ym2,ym,y,  zm,z,zp);
        myp[c] = Lop(sv, xm,x,xp,   y,yp,yp2,  zm,z,zp);
        mzm[c] = Lop(sv, xm,x,xp,   ym,y,yp,   zm2,zm,z);
        mzp[c] = Lop(sv, xm,x,xp,   ym,y,yp,   z,zp,zp2);
        vxm[c] = sv[IDX(xm,y,z)];  vxp[c] = sv[IDX(xp,y,z)];
        vym[c] = sv[IDX(x,ym,z)];  vyp[c] = sv[IDX(x,yp,z)];
        vzm[c] = sv[IDX(x,y,zm)];  vzp[c] = sv[IDX(x,y,zp)];
      }
      #pragma unroll
      for (int i=0;i<3;i++){
        float g0, g1, g2;
        if (i==0){ g0 = vxp[0]-vxm[0]; g1 = vxp[1]-vxm[1]; g2 = vxp[2]-vxm[2]; }
        else if (i==1){ g0 = vyp[0]-vym[0]; g1 = vyp[1]-vym[1]; g2 = vyp[2]-vym[2]; }
        else { g0 = vzp[0]-vzm[0]; g1 = vzp[1]-vzm[1]; g2 = vzp[2]-vzm[2]; }
        float t1 = 0.5f*(g0*mc[0] + g1*mc[1] + g2*mc[2]);
        float t2 = 0.5f*( mxp[i]*vxp[0] - mxm[i]*vxm[0]
                        + myp[i]*vyp[1] - mym[i]*vym[1]
                        + mzp[i]*vzp[2] - mzm[i]*vzm[2] );
        tb[i*N3+p] = t1 + t2;
      }
    }

    if (s == 9) break;
    if (s > 0){ float* tmp = dcur; dcur = dfree; dfree = tmp; }

    __threadfence();
    grid.sync();

    // ---- phase C: v -= dt*(I - eps*A) t ----
    for (int t = blockIdx.x; t < NT; t += G){
      const int x = t/24;
      const int y = (t%24)*4 + threadIdx.y;
      const int xm=wm(x), xp=wp(x), ym=wm(y), yp=wp(y);
      const int zm=wm(z), zp=wp(z);
      const int p = IDX(x,y,z);
      #pragma unroll
      for (int c=0;c<3;c++){
        const float* st = tb + c*N3;
        float tc = st[p];
        float sum = st[IDX(xm,y,z)] + st[IDX(xp,y,z)]
                  + st[IDX(x,ym,z)] + st[IDX(x,yp,z)]
                  + st[IDX(x,y,zm)] + st[IDX(x,y,zp)];
        float u = tc - EPS*(6.0f*tc - sum);
        v[c*N3+p] -= DT*u;
      }
    }
  }
}

extern "C" void kernel_launch(void* const* d_in, const int* in_sizes, int n_in,
                              void* d_out, int out_size, void* d_ws, size_t ws_size,
                              hipStream_t stream)
{
  const float* v0 = (const float*)d_in[0];
  float* out = (float*)d_out;
  float* ws  = (float*)d_ws;

  float* v    = ws;            // 3*N3
  float* disA = v    + 3*N3;   // 3*N3
  float* disB = disA + 3*N3;   // 3*N3
  float* tb   = disB + 3*N3;   // 3*N3

  int nb = 0;
  hipOccupancyMaxActiveBlocksPerMultiprocessor(&nb, (const void*)mega, 384, 0);
  if (nb < 1) nb = 1;
  long long grid = (long long)nb * 256;    // 256 CUs on MI355X
  if (grid > NT) grid = NT;

  void* args[] = { (void*)&v0, (void*)&v, (void*)&disA, (void*)&disB,
                   (void*)&tb, (void*)&out };
  hipLaunchCooperativeKernel((const void*)mega, dim3((unsigned)grid),
                             dim3(NN,4,1), args, 0, stream);
}

// Round 6
// 293.859 us; speedup vs baseline: 5.3078x; 5.3078x over previous
//
#include <hip/hip_runtime.h>

#define NN 96
#define N3 (96*96*96)
#define EPS 0.0025f
#define DT  0.1f

__device__ __forceinline__ int wm(int i){ return i==0    ? NN-1 : i-1; }
__device__ __forceinline__ int wp(int i){ return i==NN-1 ? 0    : i+1; }
__device__ __forceinline__ int CB(int x,int y){ return (x*NN+y)*NN; }
__device__ __forceinline__ float2 ld2(const float* __restrict__ s, int i){
  return *(const float2*)(s+i);
}
__device__ __forceinline__ void st2(float* __restrict__ s, int i, float a, float b){
  *(float2*)(s+i) = make_float2(a,b);
}
__device__ __forceinline__ float LOP(float cen, float n0,float n1,float n2,float n3,float n4,float n5){
  return fmaf(EPS, 6.f*cen - (n0+n1+n2+n3+n4+n5), cen);
}

// AoS f32 [p][3] -> SoA f32 [c][p], 4 points per thread, all-vector
__global__ void k_convert(const float* __restrict__ in, float* __restrict__ v){
  int i = blockIdx.x*256 + threadIdx.x;
  if (i >= N3/4) return;
  const float4* in4 = (const float4*)in;
  float4 a = in4[3*i], b = in4[3*i+1], c4 = in4[3*i+2];
  *(float4*)(v +        4*i) = make_float4(a.x, a.w, b.z, c4.y);
  *(float4*)(v + N3   + 4*i) = make_float4(a.y, b.x, b.w, c4.z);
  *(float4*)(v + 2*N3 + 4*i) = make_float4(a.z, b.y, c4.x, c4.w);
}

// Kernel A: dis_new = dis - dt*(grad(dis)·v + v); t = t1+t2 with m = Lv on the fly.
// 2 z-points per thread, unique-load dedup, all float2.
template<int ZERO_DIS, int LAST>
__global__ __launch_bounds__(384) void k_A(const float* __restrict__ dis,
    const float* __restrict__ v, float* __restrict__ dout,
    float* __restrict__ t, float* __restrict__ out_ilv)
{
  const int z0 = threadIdx.x*2;
  const int y  = blockIdx.x*8 + threadIdx.y;
  const int x  = blockIdx.y;
  const int xm=wm(x), xp=wp(x), xm2=wm(xm), xp2=wp(xp);
  const int ym=wm(y), yp=wp(y), ym2=wm(ym), yp2=wp(yp);
  const int zA = (z0==0)?   NN-2 : z0-2;   // pair [z0-2, z0-1]
  const int zB = (z0==NN-2)? 0   : z0+2;   // pair [z0+2, z0+3]

  const int cbC=CB(x,y), cbXm=CB(xm,y), cbXp=CB(xp,y), cbYm=CB(x,ym), cbYp=CB(x,yp);
  const int cbXm2=CB(xm2,y), cbXp2=CB(xp2,y), cbYm2=CB(x,ym2), cbYp2=CB(x,yp2);
  const int cbMM=CB(xm,ym), cbMP=CB(xm,yp), cbPM=CB(xp,ym), cbPP=CB(xp,yp);
  const int p0 = cbC + z0;

  float2 vv[3];
  #pragma unroll
  for (int c=0;c<3;c++) vv[c] = ld2(v+c*N3, p0);

  // ---- dis update ----
  float r[3][2];
  #pragma unroll
  for (int c=0;c<3;c++){
    if (ZERO_DIS){
      r[c][0] = -DT*vv[c].x; r[c][1] = -DT*vv[c].y;
    } else {
      const float* d = dis + c*N3;
      float2 D0 = ld2(d, cbC+zA), D1 = ld2(d, cbC+z0), D2 = ld2(d, cbC+zB);
      float2 Dxm = ld2(d, cbXm+z0), Dxp = ld2(d, cbXp+z0);
      float2 Dym = ld2(d, cbYm+z0), Dyp = ld2(d, cbYp+z0);
      float w0 = 0.5f*( (Dxp.x-Dxm.x)*vv[0].x + (Dyp.x-Dym.x)*vv[1].x + (D1.y-D0.y)*vv[2].x );
      float w1 = 0.5f*( (Dxp.y-Dxm.y)*vv[0].y + (Dyp.y-Dym.y)*vv[1].y + (D2.x-D1.x)*vv[2].y );
      r[c][0] = D1.x - DT*(w0 + vv[c].x);
      r[c][1] = D1.y - DT*(w1 + vv[c].y);
    }
  }
  if (LAST){
    float* ob = out_ilv + (size_t)p0*3;    // AoS: c0,c1,c2 for p0 then p0+1
    st2(ob, 0, r[0][0], r[1][0]);
    st2(ob, 2, r[2][0], r[0][1]);
    st2(ob, 4, r[1][1], r[2][1]);
    return;
  }
  #pragma unroll
  for (int c=0;c<3;c++) st2(dout + c*N3, p0, r[c][0], r[c][1]);

  // ---- t = t1 + t2, m recomputed on the fly, unique loads only ----
  float mzm[3][2], mzp[3][2], mxmF[3][2], mxpF[3][2], mymF[3][2], mypF[3][2];
  float fvx_m[2], fvx_p[2], fvy_m[2], fvy_p[2], fvz_m[2], fvz_p[2];
  float t1a[3][2] = {{0,0},{0,0},{0,0}};

  #pragma unroll
  for (int c=0;c<3;c++){
    const float* s = v + c*N3;
    const float2 C1 = vv[c];
    float2 C0  = ld2(s, cbC+zA),  C2  = ld2(s, cbC+zB);
    float2 Xma = ld2(s, cbXm+zA), Xmb = ld2(s, cbXm+z0), Xmc = ld2(s, cbXm+zB);
    float2 Xpa = ld2(s, cbXp+zA), Xpb = ld2(s, cbXp+z0), Xpc = ld2(s, cbXp+zB);
    float2 Yma = ld2(s, cbYm+zA), Ymb = ld2(s, cbYm+z0), Ymc = ld2(s, cbYm+zB);
    float2 Ypa = ld2(s, cbYp+zA), Ypb = ld2(s, cbYp+z0), Ypc = ld2(s, cbYp+zB);
    float2 Xm2 = ld2(s, cbXm2+z0), Xp2 = ld2(s, cbXp2+z0);
    float2 Ym2 = ld2(s, cbYm2+z0), Yp2 = ld2(s, cbYp2+z0);
    float2 Mm  = ld2(s, cbMM+z0),  Mp  = ld2(s, cbMP+z0);
    float2 Pm  = ld2(s, cbPM+z0),  Pp  = ld2(s, cbPP+z0);

    // m on center column at z0-1, z0, z0+1, z0+2
    float mcm1 = LOP(C0.y, C0.x, C1.x, Xma.y, Xpa.y, Yma.y, Ypa.y);
    float mc0  = LOP(C1.x, C0.y, C1.y, Xmb.x, Xpb.x, Ymb.x, Ypb.x);
    float mc1  = LOP(C1.y, C1.x, C2.x, Xmb.y, Xpb.y, Ymb.y, Ypb.y);
    float mcp2 = LOP(C2.x, C1.y, C2.y, Xmc.x, Xpc.x, Ymc.x, Ypc.x);
    mzm[c][0]=mcm1; mzm[c][1]=mc0; mzp[c][0]=mc1; mzp[c][1]=mcp2;

    // m on x/y faces at z0, z0+1
    mxmF[c][0] = LOP(Xmb.x, Xma.y, Xmb.y, Xm2.x, C1.x, Mm.x, Mp.x);
    mxmF[c][1] = LOP(Xmb.y, Xmb.x, Xmc.x, Xm2.y, C1.y, Mm.y, Mp.y);
    mxpF[c][0] = LOP(Xpb.x, Xpa.y, Xpb.y, C1.x, Xp2.x, Pm.x, Pp.x);
    mxpF[c][1] = LOP(Xpb.y, Xpb.x, Xpc.x, C1.y, Xp2.y, Pm.y, Pp.y);
    mymF[c][0] = LOP(Ymb.x, Yma.y, Ymb.y, Mm.x, Pm.x, Ym2.x, C1.x);
    mymF[c][1] = LOP(Ymb.y, Ymb.x, Ymc.x, Mm.y, Pm.y, Ym2.y, C1.y);
    mypF[c][0] = LOP(Ypb.x, Ypa.y, Ypb.y, Mp.x, Pp.x, C1.x, Yp2.x);
    mypF[c][1] = LOP(Ypb.y, Ypb.x, Ypc.x, Mp.y, Pp.y, C1.y, Yp2.y);

    // t1_i += d_i(v_c) * m_c   at both points
    t1a[0][0] = fmaf(Xpb.x-Xmb.x, mc0, t1a[0][0]);
    t1a[1][0] = fmaf(Ypb.x-Ymb.x, mc0, t1a[1][0]);
    t1a[2][0] = fmaf(C1.y -C0.y,  mc0, t1a[2][0]);
    t1a[0][1] = fmaf(Xpb.y-Xmb.y, mc1, t1a[0][1]);
    t1a[1][1] = fmaf(Ypb.y-Ymb.y, mc1, t1a[1][1]);
    t1a[2][1] = fmaf(C2.x -C1.x,  mc1, t1a[2][1]);

    if (c==0){ fvx_m[0]=Xmb.x; fvx_m[1]=Xmb.y; fvx_p[0]=Xpb.x; fvx_p[1]=Xpb.y; }
    if (c==1){ fvy_m[0]=Ymb.x; fvy_m[1]=Ymb.y; fvy_p[0]=Ypb.x; fvy_p[1]=Ypb.y; }
    if (c==2){ fvz_m[0]=C0.y;  fvz_m[1]=C1.x;  fvz_p[0]=C1.y;  fvz_p[1]=C2.x; }
  }

  #pragma unroll
  for (int i=0;i<3;i++){
    float o0 = 0.5f*( t1a[i][0]
        + mxpF[i][0]*fvx_p[0] - mxmF[i][0]*fvx_m[0]
        + mypF[i][0]*fvy_p[0] - mymF[i][0]*fvy_m[0]
        + mzp[i][0] *fvz_p[0] - mzm[i][0] *fvz_m[0] );
    float o1 = 0.5f*( t1a[i][1]
        + mxpF[i][1]*fvx_p[1] - mxmF[i][1]*fvx_m[1]
        + mypF[i][1]*fvy_p[1] - mymF[i][1]*fvy_m[1]
        + mzp[i][1] *fvz_p[1] - mzm[i][1] *fvz_m[1] );
    st2(t + i*N3, p0, o0, o1);
  }
}

// Kernel C: v -= dt * (I - eps*A) t, 2 z-points per thread
__global__ __launch_bounds__(384) void k_C(const float* __restrict__ t, float* __restrict__ v)
{
  const int z0 = threadIdx.x*2;
  const int y  = blockIdx.x*8 + threadIdx.y;
  const int x  = blockIdx.y;
  const int xm=wm(x), xp=wp(x), ym=wm(y), yp=wp(y);
  const int zA = (z0==0)?   NN-2 : z0-2;
  const int zB = (z0==NN-2)? 0   : z0+2;
  const int cbC=CB(x,y), cbXm=CB(xm,y), cbXp=CB(xp,y), cbYm=CB(x,ym), cbYp=CB(x,yp);
  const int p0 = cbC + z0;
  #pragma unroll
  for (int c=0;c<3;c++){
    const float* s = t + c*N3;
    float2 T0 = ld2(s, cbC+zA), T1 = ld2(s, cbC+z0), T2 = ld2(s, cbC+zB);
    float2 Txm = ld2(s, cbXm+z0), Txp = ld2(s, cbXp+z0);
    float2 Tym = ld2(s, cbYm+z0), Typ = ld2(s, cbYp+z0);
    float2 vc = ld2(v + c*N3, p0);
    float u0 = T1.x - EPS*(6.f*T1.x - (T0.y+T1.y+Txm.x+Txp.x+Tym.x+Typ.x));
    float u1 = T1.y - EPS*(6.f*T1.y - (T1.x+T2.x+Txm.y+Txp.y+Tym.y+Typ.y));
    st2(v + c*N3, p0, vc.x - DT*u0, vc.y - DT*u1);
  }
}

extern "C" void kernel_launch(void* const* d_in, const int* in_sizes, int n_in,
                              void* d_out, int out_size, void* d_ws, size_t ws_size,
                              hipStream_t stream)
{
  const float* v0 = (const float*)d_in[0];
  float* out = (float*)d_out;
  float* ws  = (float*)d_ws;

  float* v    = ws;            // 3*N3
  float* disA = v    + 3*N3;   // 3*N3
  float* disB = disA + 3*N3;   // 3*N3
  float* tbuf = disB + 3*N3;   // 3*N3

  dim3 blk(48,8,1), grd(12,96,1);

  k_convert<<<(N3/4+255)/256, 256, 0, stream>>>(v0, v);

  float* dcur  = disA;
  float* dfree = disB;

  for (int s=0; s<10; s++){
    if (s == 0){
      k_A<1,0><<<grd, blk, 0, stream>>>(nullptr, v, dcur, tbuf, nullptr);
    } else if (s == 9){
      k_A<0,1><<<grd, blk, 0, stream>>>(dcur, v, nullptr, nullptr, out);
      break;
    } else {
      k_A<0,0><<<grd, blk, 0, stream>>>(dcur, v, dfree, tbuf, nullptr);
      float* tmp = dcur; dcur = dfree; dfree = tmp;
    }
    k_C<<<grd, blk, 0, stream>>>(tbuf, v);
  }
}

// Round 7
// 239.209 us; speedup vs baseline: 6.5204x; 1.2285x over previous
//
#include <hip/hip_runtime.h>

#define NN 96
#define N3 (96*96*96)
#define EPS 0.0025f
#define DT  0.1f

__device__ __forceinline__ int wm(int i){ return i==0    ? NN-1 : i-1; }
__device__ __forceinline__ int wp(int i){ return i==NN-1 ? 0    : i+1; }
__device__ __forceinline__ int IDX(int x,int y,int z){ return (x*NN+y)*NN+z; }

__device__ __forceinline__ float Lop(const float* __restrict__ s,
    int xm,int x,int xp, int ym,int y,int yp, int zm,int z,int zp){
  float c = s[IDX(x,y,z)];
  float sum = s[IDX(xm,y,z)] + s[IDX(xp,y,z)]
            + s[IDX(x,ym,z)] + s[IDX(x,yp,z)]
            + s[IDX(x,y,zm)] + s[IDX(x,y,zp)];
  return fmaf(EPS, 6.0f*c - sum, c);
}

// XCD-locality swizzle: 2304 blocks, xcd = bid%8 owns x-chunk [12*xcd, 12*xcd+12).
// Within a chunk: slot = bid/8; x = 12*xcd + slot/24 (slow), ygrp = slot%24 (fast).
__device__ __forceinline__ void map_xy(int bid, int& x, int& y){
  int xcd  = bid & 7;
  int slot = bid >> 3;
  x = 12*xcd + slot/24;
  y = (slot%24)*4 + threadIdx.y;
}

// AoS f32 [p][3] -> SoA f32 [c][p]
__global__ void k_convert(const float* __restrict__ in, float* __restrict__ v){
  int i = blockIdx.x*256 + threadIdx.x;
  if (i >= N3/4) return;
  const float4* in4 = (const float4*)in;
  float4 a = in4[3*i], b = in4[3*i+1], c4 = in4[3*i+2];
  *(float4*)(v +        4*i) = make_float4(a.x, a.w, b.z, c4.y);
  *(float4*)(v + N3   + 4*i) = make_float4(a.y, b.x, b.w, c4.z);
  *(float4*)(v + 2*N3 + 4*i) = make_float4(a.z, b.y, c4.x, c4.w);
}

// Kernel A: dis_new = dis - dt*(grad(dis)·v + v), and t = t1+t2 (m = Lv on the fly).
template<int ZERO_DIS, int LAST>
__global__ __launch_bounds__(384) void k_A(const float* __restrict__ dis,
    const float* __restrict__ v, float* __restrict__ dout,
    float* __restrict__ t, float* __restrict__ out_ilv)
{
  int x, y; map_xy(blockIdx.x, x, y);
  int z = threadIdx.x;
  int xm=wm(x), xp=wp(x), xm2=wm(xm), xp2=wp(xp);
  int ym=wm(y), yp=wp(y), ym2=wm(ym), yp2=wp(yp);
  int zm=wm(z), zp=wp(z), zm2=wm(zm), zp2=wp(zp);
  int p = IDX(x,y,z);

  float vv[3] = { v[p], v[N3+p], v[2*N3+p] };

  // ---- dis update ----
  #pragma unroll
  for (int c=0;c<3;c++){
    float r;
    if (ZERO_DIS){
      r = -DT * vv[c];
    } else {
      const float* d = dis + c*N3;
      float gx = 0.5f*(d[IDX(xp,y,z)] - d[IDX(xm,y,z)]);
      float gy = 0.5f*(d[IDX(x,yp,z)] - d[IDX(x,ym,z)]);
      float gz = 0.5f*(d[IDX(x,y,zp)] - d[IDX(x,y,zm)]);
      float w  = gx*vv[0] + gy*vv[1] + gz*vv[2];
      r = d[p] - DT*(w + vv[c]);
    }
    if (LAST) out_ilv[(size_t)p*3+c] = r;
    else      dout[c*N3+p]           = r;
  }
  if (LAST) return;

  // ---- t = t1 + t2 with m computed on the fly ----
  float mc[3], mxm[3], mxp[3], mym[3], myp[3], mzm[3], mzp[3];
  float vxm[3], vxp[3], vym[3], vyp[3], vzm[3], vzp[3];
  #pragma unroll
  for (int c=0;c<3;c++){
    const float* s = v + c*N3;
    mc [c] = Lop(s, xm,x,xp,   ym,y,yp,   zm,z,zp);
    mxm[c] = Lop(s, xm2,xm,x,  ym,y,yp,   zm,z,zp);
    mxp[c] = Lop(s, x,xp,xp2,  ym,y,yp,   zm,z,zp);
    mym[c] = Lop(s, xm,x,xp,   ym2,ym,y,  zm,z,zp);
    myp[c] = Lop(s, xm,x,xp,   y,yp,yp2,  zm,z,zp);
    mzm[c] = Lop(s, xm,x,xp,   ym,y,yp,   zm2,zm,z);
    mzp[c] = Lop(s, xm,x,xp,   ym,y,yp,   z,zp,zp2);
    vxm[c] = s[IDX(xm,y,z)];  vxp[c] = s[IDX(xp,y,z)];
    vym[c] = s[IDX(x,ym,z)];  vyp[c] = s[IDX(x,yp,z)];
    vzm[c] = s[IDX(x,y,zm)];  vzp[c] = s[IDX(x,y,zp)];
  }
  #pragma unroll
  for (int i=0;i<3;i++){
    float g0, g1, g2;
    if (i==0){ g0 = vxp[0]-vxm[0]; g1 = vxp[1]-vxm[1]; g2 = vxp[2]-vxm[2]; }
    else if (i==1){ g0 = vyp[0]-vym[0]; g1 = vyp[1]-vym[1]; g2 = vyp[2]-vym[2]; }
    else { g0 = vzp[0]-vzm[0]; g1 = vzp[1]-vzm[1]; g2 = vzp[2]-vzm[2]; }
    float t1 = 0.5f*(g0*mc[0] + g1*mc[1] + g2*mc[2]);
    float t2 = 0.5f*( mxp[i]*vxp[0] - mxm[i]*vxm[0]
                    + myp[i]*vyp[1] - mym[i]*vym[1]
                    + mzp[i]*vzp[2] - mzm[i]*vzm[2] );
    t[i*N3+p] = t1 + t2;
  }
}

// Kernel C: v -= dt * (I - eps*A) t
__global__ __launch_bounds__(384) void k_C(const float* __restrict__ t, float* __restrict__ v)
{
  int x, y; map_xy(blockIdx.x, x, y);
  int z = threadIdx.x;
  int xm=wm(x), xp=wp(x), ym=wm(y), yp=wp(y);
  int zm=wm(z), zp=wp(z);
  int p = IDX(x,y,z);
  #pragma unroll
  for (int c=0;c<3;c++){
    const float* s = t + c*N3;
    float tc = s[p];
    float sum = s[IDX(xm,y,z)] + s[IDX(xp,y,z)]
              + s[IDX(x,ym,z)] + s[IDX(x,yp,z)]
              + s[IDX(x,y,zm)] + s[IDX(x,y,zp)];
    float u = tc - EPS*(6.0f*tc - sum);
    v[c*N3+p] -= DT*u;
  }
}

extern "C" void kernel_launch(void* const* d_in, const int* in_sizes, int n_in,
                              void* d_out, int out_size, void* d_ws, size_t ws_size,
                              hipStream_t stream)
{
  const float* v0 = (const float*)d_in[0];
  float* out = (float*)d_out;
  float* ws  = (float*)d_ws;

  float* v    = ws;            // 3*N3
  float* disA = v    + 3*N3;   // 3*N3
  float* disB = disA + 3*N3;   // 3*N3
  float* tbuf = disB + 3*N3;   // 3*N3

  dim3 blk(96,4,1);
  dim3 grd(2304,1,1);          // 1-D so blockIdx.x%8 == XCD round-robin slot

  k_convert<<<(N3/4+255)/256, 256, 0, stream>>>(v0, v);

  float* dcur  = disA;
  float* dfree = disB;

  for (int s=0; s<10; s++){
    if (s == 0){
      k_A<1,0><<<grd, blk, 0, stream>>>(nullptr, v, dcur, tbuf, nullptr);
    } else if (s == 9){
      k_A<0,1><<<grd, blk, 0, stream>>>(dcur, v, nullptr, nullptr, out);
      break;
    } else {
      k_A<0,0><<<grd, blk, 0, stream>>>(dcur, v, dfree, tbuf, nullptr);
      float* tmp = dcur; dcur = dfree; dfree = tmp;
    }
    k_C<<<grd, blk, 0, stream>>>(tbuf, v);
  }
}